// Round 2
// baseline (799.001 us; speedup 1.0000x reference)
//
#include <hip/hip_runtime.h>
#include <cfloat>
#include <climits>
#include <math.h>

#define NVERT 8192
#define NATOM 64
#define KNN   10
#define DIM   512
#define BATCH 32
#define NCLS  7
#define BN_EPS 1e-5f

// ---------------------------------------------------------------------------
// Kernel 1: per-(batch, atom) top-10 nearest vertices.
// Grid: BATCH*NATOM blocks x 256 threads.
// Each thread keeps a register-resident sorted top-10 (static-index bubble
// insertion so it never spills to scratch), then 10 rounds of LDS min-reduce
// over the 256 per-thread sorted heads. Tie-break: lower vertex index
// (matches jax.lax.top_k on ties).
// ---------------------------------------------------------------------------
__global__ __launch_bounds__(256) void knn_kernel(
    const float* __restrict__ pos,
    const float* __restrict__ lig,
    int* __restrict__ topk)
{
    const int bm  = blockIdx.x;       // 0 .. BATCH*NATOM-1
    const int b   = bm >> 6;
    const int m   = bm & 63;
    const int tid = threadIdx.x;

    const float* p = pos + (size_t)b * NVERT * 3;
    const float* l = lig + ((size_t)b * NATOM + m) * 3;
    const float lx = l[0], ly = l[1], lz = l[2];
    const float l2 = lx * lx + ly * ly + lz * lz;

    float bd[KNN];
    int   bi[KNN];
#pragma unroll
    for (int i = 0; i < KNN; ++i) { bd[i] = FLT_MAX; bi[i] = INT_MAX; }

    for (int n = tid; n < NVERT; n += 256) {
        const float px = p[n * 3 + 0];
        const float py = p[n * 3 + 1];
        const float pz = p[n * 3 + 2];
        // same algebraic form as reference: |p|^2 + |l|^2 - 2 p.l
        const float d2 = (px * px + py * py + pz * pz) + l2
                         - 2.0f * (px * lx + py * ly + pz * lz);
        // strict < is correct: within a thread, n is increasing, so an equal
        // d2 with larger index must not displace (lower index wins ties).
        if (d2 < bd[KNN - 1]) {
            bd[KNN - 1] = d2;
            bi[KNN - 1] = n;
#pragma unroll
            for (int j = KNN - 1; j > 0; --j) {
                const bool sw = (bd[j] < bd[j - 1]) ||
                                (bd[j] == bd[j - 1] && bi[j] < bi[j - 1]);
                if (sw) {
                    float td = bd[j]; bd[j] = bd[j - 1]; bd[j - 1] = td;
                    int   ti = bi[j]; bi[j] = bi[j - 1]; bi[j - 1] = ti;
                }
            }
        }
    }

    __shared__ float sD[256 * KNN];
    __shared__ int   sI[256 * KNN];
#pragma unroll
    for (int i = 0; i < KNN; ++i) {
        sD[tid * KNN + i] = bd[i];
        sI[tid * KNN + i] = bi[i];
    }

    __shared__ float rD[256];
    __shared__ int   rI[256];

    int head = 0;
    int* out = topk + (size_t)bm * KNN;

    for (int r = 0; r < KNN; ++r) {
        const float cd = (head < KNN) ? sD[tid * KNN + head] : FLT_MAX;
        const int   ci = (head < KNN) ? sI[tid * KNN + head] : INT_MAX;
        rD[tid] = cd;
        rI[tid] = ci;
        __syncthreads();
        for (int s = 128; s > 0; s >>= 1) {
            if (tid < s) {
                const float od = rD[tid + s];
                const int   oi = rI[tid + s];
                if (od < rD[tid] || (od == rD[tid] && oi < rI[tid])) {
                    rD[tid] = od;
                    rI[tid] = oi;
                }
            }
            __syncthreads();
        }
        const int win = rI[0];
        if (tid == 0) out[r] = win;
        // vertex indices are unique across threads -> safe to match on index
        if (ci == win) head++;
        __syncthreads();
    }
}

// ---------------------------------------------------------------------------
// Kernel 2: dedup + masked mean over selected feats rows.
// Grid: BATCH blocks x 512 threads (thread = feature dim).
// Reads only the <=640 selected rows (~39 MB total) instead of the dense
// 512 MB mask@feats contraction.
// ---------------------------------------------------------------------------
__global__ __launch_bounds__(512) void pool_kernel(
    const float* __restrict__ feats,
    const int* __restrict__ topk,
    float* __restrict__ x)
{
    const int b   = blockIdx.x;
    const int tid = threadIdx.x;

    __shared__ unsigned char mask[NVERT];
    __shared__ int list[NATOM * KNN];
    __shared__ int cnt;

    for (int n = tid; n < NVERT; n += 512) mask[n] = 0;
    if (tid == 0) cnt = 0;
    __syncthreads();

    const int* tk = topk + (size_t)b * NATOM * KNN;
    for (int j = tid; j < NATOM * KNN; j += 512) mask[tk[j]] = 1;
    __syncthreads();

    for (int n = tid; n < NVERT; n += 512) {
        if (mask[n]) {
            const int pp = atomicAdd(&cnt, 1);
            list[pp] = n;
        }
    }
    __syncthreads();

    const int count = cnt;
    const float* fb = feats + (size_t)b * NVERT * DIM;
    float acc = 0.0f;
    for (int j = 0; j < count; ++j) {
        acc += fb[(size_t)list[j] * DIM + tid];   // coalesced across lanes
    }
    x[(size_t)b * DIM + tid] = acc / (float)count;
}

// ---------------------------------------------------------------------------
// Kernel 3: h = x @ W1^T + b1.  Grid: BATCH x 512 (thread = output dim).
// ---------------------------------------------------------------------------
__global__ __launch_bounds__(512) void fc1_kernel(
    const float* __restrict__ x,
    const float* __restrict__ W1,
    const float* __restrict__ b1,
    float* __restrict__ h)
{
    const int b = blockIdx.x;
    const int d = threadIdx.x;

    __shared__ float xs[DIM];
    xs[d] = x[(size_t)b * DIM + d];
    __syncthreads();

    const float4* wr = (const float4*)(W1 + (size_t)d * DIM);
    float acc = b1[d];
#pragma unroll 4
    for (int k4 = 0; k4 < DIM / 4; ++k4) {
        const float4 w = wr[k4];
        acc += xs[4 * k4 + 0] * w.x + xs[4 * k4 + 1] * w.y +
               xs[4 * k4 + 2] * w.z + xs[4 * k4 + 3] * w.w;
    }
    h[(size_t)b * DIM + d] = acc;
}

// ---------------------------------------------------------------------------
// Kernel 4: batch-norm statistics over the batch axis (two-pass, matches
// jnp.var semantics). Grid: 1 x 512 (thread = dim).
// ---------------------------------------------------------------------------
__global__ __launch_bounds__(512) void bnstats_kernel(
    const float* __restrict__ h,
    float* __restrict__ mu,
    float* __restrict__ var)
{
    const int d = threadIdx.x;
    float s = 0.0f;
    for (int b = 0; b < BATCH; ++b) s += h[(size_t)b * DIM + d];
    const float m = s * (1.0f / BATCH);
    float q = 0.0f;
    for (int b = 0; b < BATCH; ++b) {
        const float t = h[(size_t)b * DIM + d] - m;
        q += t * t;
    }
    mu[d]  = m;
    var[d] = q * (1.0f / BATCH);
}

// ---------------------------------------------------------------------------
// Kernel 5: BN apply + SiLU + final linear (C=7). Grid: BATCH x 512.
// Waves 0..6 each shuffle-reduce one output channel.
// ---------------------------------------------------------------------------
__global__ __launch_bounds__(512) void head_kernel(
    const float* __restrict__ h,
    const float* __restrict__ mu,
    const float* __restrict__ var,
    const float* __restrict__ gamma,
    const float* __restrict__ beta,
    const float* __restrict__ W2,
    const float* __restrict__ b2,
    float* __restrict__ out)
{
    const int b   = blockIdx.x;
    const int tid = threadIdx.x;

    __shared__ float s[DIM];
    const float v  = h[(size_t)b * DIM + tid];
    const float hn = gamma[tid] * (v - mu[tid]) * rsqrtf(var[tid] + BN_EPS)
                     + beta[tid];
    s[tid] = hn / (1.0f + expf(-hn));   // silu = x * sigmoid(x)
    __syncthreads();

    const int w    = tid >> 6;   // wave id
    const int lane = tid & 63;
    if (w < NCLS) {
        float acc = 0.0f;
        for (int d = lane; d < DIM; d += 64)
            acc += s[d] * W2[(size_t)w * DIM + d];
        for (int off = 32; off > 0; off >>= 1)
            acc += __shfl_down(acc, off);
        if (lane == 0) out[(size_t)b * NCLS + w] = acc + b2[w];
    }
}

// ---------------------------------------------------------------------------
extern "C" void kernel_launch(void* const* d_in, const int* in_sizes, int n_in,
                              void* d_out, int out_size, void* d_ws, size_t ws_size,
                              hipStream_t stream)
{
    const float* pos   = (const float*)d_in[0];
    const float* feats = (const float*)d_in[1];
    const float* lig   = (const float*)d_in[2];
    const float* W1    = (const float*)d_in[3];
    const float* b1    = (const float*)d_in[4];
    const float* gamma = (const float*)d_in[5];
    const float* beta  = (const float*)d_in[6];
    const float* W2    = (const float*)d_in[7];
    const float* b2    = (const float*)d_in[8];
    float* out = (float*)d_out;

    char* ws = (char*)d_ws;
    int*   topk = (int*)ws;                                   // 32*64*10 ints = 80 KB
    float* x    = (float*)(ws + 81920);                       // 32*512 f32  = 64 KB
    float* h    = (float*)(ws + 81920 + 65536);               // 32*512 f32  = 64 KB
    float* mu   = (float*)(ws + 81920 + 65536 + 65536);       // 512 f32
    float* var  = (float*)(ws + 81920 + 65536 + 65536 + 2048);// 512 f32

    knn_kernel<<<BATCH * NATOM, 256, 0, stream>>>(pos, lig, topk);
    pool_kernel<<<BATCH, 512, 0, stream>>>(feats, topk, x);
    fc1_kernel<<<BATCH, 512, 0, stream>>>(x, W1, b1, h);
    bnstats_kernel<<<1, 512, 0, stream>>>(h, mu, var);
    head_kernel<<<BATCH, 512, 0, stream>>>(h, mu, var, gamma, beta, W2, b2, out);
}

// Round 6
// 762.558 us; speedup vs baseline: 1.0478x; 1.0478x over previous
//
#include <hip/hip_runtime.h>
#include <cfloat>
#include <climits>
#include <math.h>

#define NVERT 8192
#define NATOM 64
#define KNN   10
#define DIM   512
#define BATCH 32
#define NCLS  7
#define CH    16          // pool gather chunks per batch
#define BN_EPS 1e-5f

// ---------------------------------------------------------------------------
// Kernel 1: per-(batch, atom) top-10 nearest vertices.
// Grid: BATCH*NATOM blocks x 256 threads (4 waves).
// Per-thread sorted top-10 in registers (static-index shifts only -> no
// scratch), then per-wave top-10 via 10 rounds of barrier-free shfl_xor
// lexicographic-min pops, then ONE barrier + wave-0 merge of the 4x10
// candidates. Tie-break: lower vertex index (matches jax.lax.top_k).
// ---------------------------------------------------------------------------
__global__ __launch_bounds__(256) void knn_kernel(
    const float* __restrict__ pos,
    const float* __restrict__ lig,
    int* __restrict__ topk)
{
    const int bm   = blockIdx.x;      // 0 .. BATCH*NATOM-1
    const int b    = bm >> 6;
    const int m    = bm & 63;
    const int tid  = threadIdx.x;
    const int lane = tid & 63;
    const int wave = tid >> 6;

    const float* p = pos + (size_t)b * NVERT * 3;
    const float* l = lig + ((size_t)b * NATOM + m) * 3;
    const float lx = l[0], ly = l[1], lz = l[2];
    const float l2 = lx * lx + ly * ly + lz * lz;

    float bd[KNN];
    int   bi[KNN];
#pragma unroll
    for (int i = 0; i < KNN; ++i) { bd[i] = FLT_MAX; bi[i] = INT_MAX; }

    for (int n = tid; n < NVERT; n += 256) {
        const float px = p[n * 3 + 0];
        const float py = p[n * 3 + 1];
        const float pz = p[n * 3 + 2];
        // same algebraic form as reference: |p|^2 + |l|^2 - 2 p.l
        const float d2 = (px * px + py * py + pz * pz) + l2
                         - 2.0f * (px * lx + py * ly + pz * lz);
        if (d2 < bd[KNN - 1]) {
            bd[KNN - 1] = d2;
            bi[KNN - 1] = n;
#pragma unroll
            for (int j = KNN - 1; j > 0; --j) {
                const bool sw = (bd[j] < bd[j - 1]) ||
                                (bd[j] == bd[j - 1] && bi[j] < bi[j - 1]);
                if (sw) {
                    float td = bd[j]; bd[j] = bd[j - 1]; bd[j - 1] = td;
                    int   ti = bi[j]; bi[j] = bi[j - 1]; bi[j - 1] = ti;
                }
            }
        }
    }

    // ---- per-wave top-10 (no barriers) ----
    __shared__ float sD[4 * KNN];
    __shared__ int   sI[4 * KNN];

    for (int r = 0; r < KNN; ++r) {
        float cd = bd[0];
        int   ci = bi[0];
#pragma unroll
        for (int off = 1; off < 64; off <<= 1) {
            const float od = __shfl_xor(cd, off);
            const int   oi = __shfl_xor(ci, off);
            if (od < cd || (od == cd && oi < ci)) { cd = od; ci = oi; }
        }
        if (lane == 0) { sD[wave * KNN + r] = cd; sI[wave * KNN + r] = ci; }
        // vertex indices are unique within the block -> exactly one lane pops
        if (bi[0] == ci) {
#pragma unroll
            for (int j = 0; j < KNN - 1; ++j) { bd[j] = bd[j + 1]; bi[j] = bi[j + 1]; }
            bd[KNN - 1] = FLT_MAX;
            bi[KNN - 1] = INT_MAX;
        }
    }
    __syncthreads();

    // ---- wave 0 merges the 4 sorted lists (40 candidates, one per lane) ----
    if (wave == 0) {
        float cd = (lane < 4 * KNN) ? sD[lane] : FLT_MAX;
        int   ci = (lane < 4 * KNN) ? sI[lane] : INT_MAX;
        int* out = topk + (size_t)bm * KNN;
        for (int r = 0; r < KNN; ++r) {
            float wd = cd;
            int   wi = ci;
#pragma unroll
            for (int off = 1; off < 64; off <<= 1) {
                const float od = __shfl_xor(wd, off);
                const int   oi = __shfl_xor(wi, off);
                if (od < wd || (od == wd && oi < wi)) { wd = od; wi = oi; }
            }
            if (lane == 0) out[r] = wi;
            if (ci == wi) { cd = FLT_MAX; ci = INT_MAX; }   // pop winner
        }
    }
}

// ---------------------------------------------------------------------------
// Kernel 2a: dedup -> compacted vertex list + count per batch.
// Grid: BATCH x 512.
// ---------------------------------------------------------------------------
__global__ __launch_bounds__(512) void pool_list_kernel(
    const int* __restrict__ topk,
    int* __restrict__ list,
    int* __restrict__ cnt)
{
    const int b   = blockIdx.x;
    const int tid = threadIdx.x;

    __shared__ unsigned char mask[NVERT];
    __shared__ int c;

    for (int n = tid; n < NVERT; n += 512) mask[n] = 0;
    if (tid == 0) c = 0;
    __syncthreads();

    const int* tk = topk + (size_t)b * NATOM * KNN;
    for (int j = tid; j < NATOM * KNN; j += 512) mask[tk[j]] = 1;
    __syncthreads();

    int* lb = list + (size_t)b * (NATOM * KNN);
    for (int n = tid; n < NVERT; n += 512) {
        if (mask[n]) lb[atomicAdd(&c, 1)] = n;
    }
    __syncthreads();
    if (tid == 0) cnt[b] = c;
}

// ---------------------------------------------------------------------------
// Kernel 2b: parallel gather of selected rows.
// Grid: BATCH*CH blocks x 512 (thread = feature dim). Block (b,c) sums rows
// j = c, c+CH, c+2CH, ... 4-way unrolled so 4 HBM row-loads are in flight.
// ---------------------------------------------------------------------------
__global__ __launch_bounds__(512) void pool_gather_kernel(
    const float* __restrict__ feats,
    const int* __restrict__ list,
    const int* __restrict__ cnt,
    float* __restrict__ partial)
{
    const int bc  = blockIdx.x;
    const int b   = bc / CH;
    const int c   = bc % CH;
    const int tid = threadIdx.x;

    const int count  = cnt[b];
    const int* lb    = list + (size_t)b * (NATOM * KNN);
    const float* fb  = feats + (size_t)b * NVERT * DIM;

    float a0 = 0.f, a1 = 0.f, a2 = 0.f, a3 = 0.f;
    int j = c;
    for (; j + 3 * CH < count; j += 4 * CH) {
        const int i0 = lb[j];
        const int i1 = lb[j + CH];
        const int i2 = lb[j + 2 * CH];
        const int i3 = lb[j + 3 * CH];
        a0 += fb[(size_t)i0 * DIM + tid];
        a1 += fb[(size_t)i1 * DIM + tid];
        a2 += fb[(size_t)i2 * DIM + tid];
        a3 += fb[(size_t)i3 * DIM + tid];
    }
    for (; j < count; j += CH) a0 += fb[(size_t)lb[j] * DIM + tid];

    partial[((size_t)b * CH + c) * DIM + tid] = (a0 + a1) + (a2 + a3);
}

// ---------------------------------------------------------------------------
// Kernel 3: reduce partials -> x, then h = x @ W1^T + b1 (fused).
// Grid: BATCH x 512 (thread = output dim).
// ---------------------------------------------------------------------------
__global__ __launch_bounds__(512) void fc1_kernel(
    const float* __restrict__ partial,
    const int* __restrict__ cnt,
    const float* __restrict__ W1,
    const float* __restrict__ b1,
    float* __restrict__ h)
{
    const int b = blockIdx.x;
    const int d = threadIdx.x;

    __shared__ float xs[DIM];
    float s = 0.f;
#pragma unroll
    for (int c = 0; c < CH; ++c)
        s += partial[((size_t)b * CH + c) * DIM + d];
    xs[d] = s / (float)cnt[b];
    __syncthreads();

    const float4* wr = (const float4*)(W1 + (size_t)d * DIM);
    float acc = b1[d];
#pragma unroll 4
    for (int k4 = 0; k4 < DIM / 4; ++k4) {
        const float4 w = wr[k4];
        acc += xs[4 * k4 + 0] * w.x + xs[4 * k4 + 1] * w.y +
               xs[4 * k4 + 2] * w.z + xs[4 * k4 + 3] * w.w;
    }
    h[(size_t)b * DIM + d] = acc;
}

// ---------------------------------------------------------------------------
// Kernel 4: batch-norm statistics over the batch axis (two-pass, matches
// jnp.var semantics). Grid: 1 x 512 (thread = dim).
// ---------------------------------------------------------------------------
__global__ __launch_bounds__(512) void bnstats_kernel(
    const float* __restrict__ h,
    float* __restrict__ mu,
    float* __restrict__ var)
{
    const int d = threadIdx.x;
    float s = 0.0f;
    for (int b = 0; b < BATCH; ++b) s += h[(size_t)b * DIM + d];
    const float m = s * (1.0f / BATCH);
    float q = 0.0f;
    for (int b = 0; b < BATCH; ++b) {
        const float t = h[(size_t)b * DIM + d] - m;
        q += t * t;
    }
    mu[d]  = m;
    var[d] = q * (1.0f / BATCH);
}

// ---------------------------------------------------------------------------
// Kernel 5: BN apply + SiLU + final linear (C=7). Grid: BATCH x 512.
// Waves 0..6 each shuffle-reduce one output channel.
// ---------------------------------------------------------------------------
__global__ __launch_bounds__(512) void head_kernel(
    const float* __restrict__ h,
    const float* __restrict__ mu,
    const float* __restrict__ var,
    const float* __restrict__ gamma,
    const float* __restrict__ beta,
    const float* __restrict__ W2,
    const float* __restrict__ b2,
    float* __restrict__ out)
{
    const int b   = blockIdx.x;
    const int tid = threadIdx.x;

    __shared__ float s[DIM];
    const float v  = h[(size_t)b * DIM + tid];
    const float hn = gamma[tid] * (v - mu[tid]) * rsqrtf(var[tid] + BN_EPS)
                     + beta[tid];
    s[tid] = hn / (1.0f + expf(-hn));   // silu = x * sigmoid(x)
    __syncthreads();

    const int w    = tid >> 6;   // wave id
    const int lane = tid & 63;
    if (w < NCLS) {
        float acc = 0.0f;
        for (int d = lane; d < DIM; d += 64)
            acc += s[d] * W2[(size_t)w * DIM + d];
        for (int off = 32; off > 0; off >>= 1)
            acc += __shfl_down(acc, off);
        if (lane == 0) out[(size_t)b * NCLS + w] = acc + b2[w];
    }
}

// ---------------------------------------------------------------------------
extern "C" void kernel_launch(void* const* d_in, const int* in_sizes, int n_in,
                              void* d_out, int out_size, void* d_ws, size_t ws_size,
                              hipStream_t stream)
{
    const float* pos   = (const float*)d_in[0];
    const float* feats = (const float*)d_in[1];
    const float* lig   = (const float*)d_in[2];
    const float* W1    = (const float*)d_in[3];
    const float* b1    = (const float*)d_in[4];
    const float* gamma = (const float*)d_in[5];
    const float* beta  = (const float*)d_in[6];
    const float* W2    = (const float*)d_in[7];
    const float* b2    = (const float*)d_in[8];
    float* out = (float*)d_out;

    char* ws = (char*)d_ws;
    int*   topk    = (int*)(ws + 0);               // 32*64*10 ints = 80 KB
    int*   list    = (int*)(ws + 81920);           // 32*640 ints   = 80 KB
    int*   cnt     = (int*)(ws + 163840);          // 32 ints
    float* partial = (float*)(ws + 196608);        // 32*16*512 f32 = 1 MB
    float* h       = (float*)(ws + 196608 + 1048576);            // 64 KB
    float* mu      = (float*)(ws + 196608 + 1048576 + 65536);    // 2 KB
    float* var     = (float*)(ws + 196608 + 1048576 + 65536 + 2048);

    knn_kernel<<<BATCH * NATOM, 256, 0, stream>>>(pos, lig, topk);
    pool_list_kernel<<<BATCH, 512, 0, stream>>>(topk, list, cnt);
    pool_gather_kernel<<<BATCH * CH, 512, 0, stream>>>(feats, list, cnt, partial);
    fc1_kernel<<<BATCH, 512, 0, stream>>>(partial, cnt, W1, b1, h);
    bnstats_kernel<<<1, 512, 0, stream>>>(h, mu, var);
    head_kernel<<<BATCH, 512, 0, stream>>>(h, mu, var, gamma, beta, W2, b2, out);
}